// Round 13
// baseline (141.005 us; speedup 1.0000x reference)
//
#include <hip/hip_runtime.h>

#define KN 1000000
#define NCOLS 70400
#define NPAIRS (KN / 32)          // 2 elem-tiles (32 elems) per wave-iteration
#define NBLK 1024
#define NTHR 256

typedef _Float16 f16x8 __attribute__((ext_vector_type(8)));
typedef _Float16 h2    __attribute__((ext_vector_type(2)));
typedef float    f32x4 __attribute__((ext_vector_type(4)));
typedef int      i32x4 __attribute__((ext_vector_type(4)));
union F8 { f16x8 f; i32x4 i; };

__device__ __forceinline__ unsigned encodeF(float f) {
    unsigned b = __float_as_uint(f);
    return (b & 0x80000000u) ? ~b : (b | 0x80000000u);
}
__device__ __forceinline__ float decodeF(unsigned e) {
    unsigned b = (e & 0x80000000u) ? (e & 0x7fffffffu) : ~e;
    return __uint_as_float(b);
}
#define ENC_SENT 0x34E76980u   // encodeF(-9999999.0f)

#define MFMA16(a, b, c) __builtin_amdgcn_mfma_f32_16x16x32_f16((a), (b), (c), 0, 0, 0)

__device__ __forceinline__ int h2i(h2 h) { int i; __builtin_memcpy(&i, &h, 4); return i; }
__device__ __forceinline__ h2 hmax2z(h2 a) { return __builtin_elementwise_max(a, (h2)(_Float16)0); }
__device__ __forceinline__ h2 pk(float lo, float hi) { return (h2){(_Float16)lo, (_Float16)hi}; }

// LDS layout of raw fp32 weights (staged coalesced once per block):
#define OW1 0
#define OB1 72
#define OW2 90
#define OB2 738
#define OW3 774
#define OB3 2070
#define OW4 2106
#define OB4 2142
#define NWTS 2143

// Orientation: D(out x elem) = A(W, out x in) . B(hidden, in x elem).
//   B[k][n]: n = lane&15 = ELEM, k = quad*8+j  -> elem stays on lane&15 forever.
//   D[m][n]: n = elem, m = out-feat = 16*T + quad*4 + r.
// D -> next-layer-B: for B b32-slot s (halfs = feats 8qd'+2s, +1):
//   pack = regs(0,1) if s even else regs(2,3)  [compile-time]
//   src tile T = qd'>>1                         [data-select AFTER bpermute]
//   src lane  = 16*((2qd' + (s>>1)) & 3) + e
// R12 BUG: bpermute inside a divergent ternary -> pulls from exec-masked-off
// lanes = undefined. FIX: all bpermutes unconditional (full exec), then
// v_cndmask on the fetched data.

__global__ __launch_bounds__(NTHR)
__attribute__((amdgpu_waves_per_eu(3, 3)))
void mlp_scatter_mfma(const float* __restrict__ x, const int* __restrict__ tidx,
                      const float* __restrict__ W1, const float* __restrict__ b1,
                      const float* __restrict__ W2, const float* __restrict__ b2,
                      const float* __restrict__ W3, const float* __restrict__ b3,
                      const float* __restrict__ W4, const float* __restrict__ b4,
                      unsigned* __restrict__ outU)
{
    __shared__ float sw[NWTS];

    const int t    = threadIdx.x;
    const int lane = t & 63;
    const int qd   = (lane >> 4) & 3;
    const int e    = lane & 15;

    // ---- coalesced one-time stage of all weights into LDS ----
    for (int i = t; i < 72;   i += NTHR) sw[OW1 + i] = W1[i];
    for (int i = t; i < 18;   i += NTHR) sw[OB1 + i] = b1[i];
    for (int i = t; i < 648;  i += NTHR) sw[OW2 + i] = W2[i];
    for (int i = t; i < 36;   i += NTHR) sw[OB2 + i] = b2[i];
    for (int i = t; i < 1296; i += NTHR) sw[OW3 + i] = W3[i];
    for (int i = t; i < 36;   i += NTHR) sw[OB3 + i] = b3[i];
    for (int i = t; i < 36;   i += NTHR) sw[OW4 + i] = W4[i];
    if (t == 0) sw[OB4] = b4[0];
    __syncthreads();

    // ---- L1 weights, packed f16x2 over row pairs (rows 8*qd+2j2, +1) ----
    h2 w1p[4][4], b1p[4];
#pragma unroll
    for (int j2 = 0; j2 < 4; ++j2) {
        const int r0 = 8 * qd + 2 * j2, r1 = r0 + 1;
#pragma unroll
        for (int c = 0; c < 4; ++c) {
            float fa = (r0 < 18) ? sw[OW1 + r0 * 4 + c] : 0.0f;
            float fb = (r1 < 18) ? sw[OW1 + r1 * 4 + c] : 0.0f;
            w1p[j2][c] = pk(fa, fb);
        }
        b1p[j2] = pk((r0 < 18) ? sw[OB1 + r0] : 0.0f,
                     (r1 < 18) ? sw[OB1 + r1] : 0.0f);
    }

    // ---- A-fragments (weights stationary): A[m][k]: m=16T+e, k=32ks+8qd+j ----
    auto af = [&](int off, int OUT, int IN, int T, int ks) {
        F8 r;
#pragma unroll
        for (int j = 0; j < 8; ++j) {
            const int row = 16 * T + e, k = 32 * ks + 8 * qd + j;
            r.f[j] = (_Float16)((row < OUT && k < IN) ? sw[off + row * IN + k] : 0.0f);
        }
        return r.f;
    };
    const f16x8 A2_0 = af(OW2, 36, 18, 0, 0), A2_1 = af(OW2, 36, 18, 1, 0), A2_2 = af(OW2, 36, 18, 2, 0);
    const f16x8 A30_0 = af(OW3, 36, 36, 0, 0), A31_0 = af(OW3, 36, 36, 0, 1);
    const f16x8 A30_1 = af(OW3, 36, 36, 1, 0), A31_1 = af(OW3, 36, 36, 1, 1);
    const f16x8 A30_2 = af(OW3, 36, 36, 2, 0), A31_2 = af(OW3, 36, 36, 2, 1);

    // ---- per-lane bias/W4 vectors over D rows m = 16T + 4qd + r ----
    auto bvec = [&](int off, int T) {
        f32x4 v;
#pragma unroll
        for (int r = 0; r < 4; ++r) {
            const int m = 16 * T + 4 * qd + r;
            v[r] = (m < 36) ? sw[off + m] : 0.0f;
        }
        return v;
    };
    const f32x4 B2V0 = bvec(OB2, 0), B2V1 = bvec(OB2, 1), B2V2 = bvec(OB2, 2);
    const f32x4 B3V0 = bvec(OB3, 0), B3V1 = bvec(OB3, 1), B3V2 = bvec(OB3, 2);
    const f32x4 W4V0 = bvec(OW4, 0), W4V1 = bvec(OW4, 1), W4V2 = bvec(OW4, 2);
    const float b4s = sw[OB4];

    // ---- bpermute lane indices (bytes): src lane = 16*qs + e ----
    const int idxA = ((((2 * qd) & 3) << 4) | e) << 2;       // slots 0,1
    const int idxB = ((((2 * qd + 1) & 3) << 4) | e) << 2;   // slots 2,3
    const int idxE = e << 2;                                 // ks=1 slots (src quad 0)
    const bool lowT = (qd < 2);
    const bool q0   = (qd == 0);

    const int gw = (blockIdx.x * blockDim.x + t) >> 6;
    const int nw = (gridDim.x * blockDim.x) >> 6;

    // one elem-tile pipeline: x(4) + col -> atomic
    auto tile = [&](float x0, float x1, float x2, float x3, int col) {
        // L1 in packed f16 VALU -> B2 frag directly (fp-contract -> v_pk_fma_f16)
        const h2 xp0 = pk(x0, x0), xp1 = pk(x1, x1);
        const h2 xp2 = pk(x2, x2), xp3 = pk(x3, x3);
        F8 b2f;
#pragma unroll
        for (int j2 = 0; j2 < 4; ++j2) {
            h2 a = b1p[j2];
            a = w1p[j2][0] * xp0 + a;
            a = w1p[j2][1] * xp1 + a;
            a = w1p[j2][2] * xp2 + a;
            a = w1p[j2][3] * xp3 + a;
            b2f.i[j2] = h2i(hmax2z(a));
        }
        // L2: 3 MFMAs (bias pre-loaded in C)
        const f32x4 D0 = MFMA16(A2_0, b2f.f, B2V0);
        const f32x4 D1 = MFMA16(A2_1, b2f.f, B2V1);
        const f32x4 D2 = MFMA16(A2_2, b2f.f, B2V2);
        // relu + pack to f16 pairs
        const int p01_0 = h2i(hmax2z(pk(D0[0], D0[1])));
        const int p23_0 = h2i(hmax2z(pk(D0[2], D0[3])));
        const int p01_1 = h2i(hmax2z(pk(D1[0], D1[1])));
        const int p23_1 = h2i(hmax2z(pk(D1[2], D1[3])));
        const int p01_2 = h2i(hmax2z(pk(D2[0], D2[1])));
        const int p23_2 = h2i(hmax2z(pk(D2[2], D2[3])));
        // D -> B3 transform: ALL bpermutes at full exec, select on data after
        const int tA00 = __builtin_amdgcn_ds_bpermute(idxA, p01_0);
        const int tA01 = __builtin_amdgcn_ds_bpermute(idxA, p01_1);
        const int tA20 = __builtin_amdgcn_ds_bpermute(idxA, p23_0);
        const int tA21 = __builtin_amdgcn_ds_bpermute(idxA, p23_1);
        const int tB00 = __builtin_amdgcn_ds_bpermute(idxB, p01_0);
        const int tB01 = __builtin_amdgcn_ds_bpermute(idxB, p01_1);
        const int tB20 = __builtin_amdgcn_ds_bpermute(idxB, p23_0);
        const int tB21 = __builtin_amdgcn_ds_bpermute(idxB, p23_1);
        const int u0   = __builtin_amdgcn_ds_bpermute(idxE, p01_2);
        const int u1   = __builtin_amdgcn_ds_bpermute(idxE, p23_2);
        const int s0 = lowT ? tA00 : tA01;
        const int s1 = lowT ? tA20 : tA21;
        const int s2 = lowT ? tB00 : tB01;
        const int s3 = lowT ? tB20 : tB21;
        F8 b30, b31;
        b30.i = (i32x4){s0, s1, s2, s3};
        b31.i = (i32x4){q0 ? u0 : 0, q0 ? u1 : 0, 0, 0};
        // L3: 6 MFMAs
        f32x4 E0 = MFMA16(A30_0, b30.f, B3V0); E0 = MFMA16(A31_0, b31.f, E0);
        f32x4 E1 = MFMA16(A30_1, b30.f, B3V1); E1 = MFMA16(A31_1, b31.f, E1);
        f32x4 E2 = MFMA16(A30_2, b30.f, B3V2); E2 = MFMA16(A31_2, b31.f, E2);
        // L4 dot in VALU + cross-quad reduce (2 shuffles)
        float v = 0.0f;
#pragma unroll
        for (int r = 0; r < 4; ++r) {
            v = fmaf(W4V0[r], fmaxf(E0[r], 0.0f), v);
            v = fmaf(W4V1[r], fmaxf(E1[r], 0.0f), v);
            v = fmaf(W4V2[r], fmaxf(E2[r], 0.0f), v);
        }
        v += __shfl_xor(v, 16);
        v += __shfl_xor(v, 32);
        if (lane < 16) atomicMax(&outU[col], encodeF(v + b4s) - ENC_SENT);
    };

    // ---- prefetch-rotate over pairs ----
    float cxa0, cxa1, cxa2, cxa3, cxb0, cxb1, cxb2, cxb3;
    int cca = 0, ccb = 0;
    if (gw < NPAIRS) {
        const int kb = gw * 32;
        cxa0 = x[0 * KN + kb + e];      cxb0 = x[0 * KN + kb + 16 + e];
        cxa1 = x[1 * KN + kb + e];      cxb1 = x[1 * KN + kb + 16 + e];
        cxa2 = x[2 * KN + kb + e];      cxb2 = x[2 * KN + kb + 16 + e];
        cxa3 = x[3 * KN + kb + e];      cxb3 = x[3 * KN + kb + 16 + e];
        cca  = ((const int2*)tidx)[kb + e].y;
        ccb  = ((const int2*)tidx)[kb + 16 + e].y;
    }

    for (int p = gw; p < NPAIRS; ) {
        const int pn = p + nw;
        const float xa0 = cxa0, xa1 = cxa1, xa2 = cxa2, xa3 = cxa3;
        const float xb0 = cxb0, xb1 = cxb1, xb2 = cxb2, xb3 = cxb3;
        const int cola = cca, colb = ccb;
        if (pn < NPAIRS) {
            const int kb = pn * 32;
            cxa0 = x[0 * KN + kb + e];      cxb0 = x[0 * KN + kb + 16 + e];
            cxa1 = x[1 * KN + kb + e];      cxb1 = x[1 * KN + kb + 16 + e];
            cxa2 = x[2 * KN + kb + e];      cxb2 = x[2 * KN + kb + 16 + e];
            cxa3 = x[3 * KN + kb + e];      cxb3 = x[3 * KN + kb + 16 + e];
            cca  = ((const int2*)tidx)[kb + e].y;
            ccb  = ((const int2*)tidx)[kb + 16 + e].y;
        }
        tile(xa0, xa1, xa2, xa3, cola);
        tile(xb0, xb1, xb2, xb3, colb);
        p = pn;
    }
}

__global__ __launch_bounds__(256) void init_kernel(unsigned* __restrict__ outU) {
    int gid = blockIdx.x * blockDim.x + threadIdx.x;
    if (gid < NCOLS) outU[gid] = 0u;   // == encode(SENTINEL) - bias
}

__global__ __launch_bounds__(256) void decode_kernel(unsigned* __restrict__ outU,
                                                     int out_size) {
    int gid = blockIdx.x * blockDim.x + threadIdx.x;
    if (gid < out_size) {
        float r = (gid < NCOLS) ? decodeF(outU[gid] + ENC_SENT) : 1.0f;
        ((float*)outU)[gid] = r;
    }
}

extern "C" void kernel_launch(void* const* d_in, const int* in_sizes, int n_in,
                              void* d_out, int out_size, void* d_ws, size_t ws_size,
                              hipStream_t stream) {
    const float* x    = (const float*)d_in[0];   // (1,4,1,K)
    const int*   tidx = (const int*)d_in[1];     // (K,2)
    const float* W1 = (const float*)d_in[2];
    const float* b1 = (const float*)d_in[3];
    const float* W2 = (const float*)d_in[4];
    const float* b2 = (const float*)d_in[5];
    const float* W3 = (const float*)d_in[6];
    const float* b3 = (const float*)d_in[7];
    const float* W4 = (const float*)d_in[8];
    const float* b4 = (const float*)d_in[9];
    unsigned* outU = (unsigned*)d_out;

    init_kernel<<<(NCOLS + 255) / 256, 256, 0, stream>>>(outU);

    mlp_scatter_mfma<<<NBLK, NTHR, 0, stream>>>(
        x, tidx, W1, b1, W2, b2, W3, b3, W4, b4, outU);

    decode_kernel<<<(out_size + 255) / 256, 256, 0, stream>>>(outU, out_size);
}